// Round 14
// baseline (86.324 us; speedup 1.0000x reference)
//
#include <hip/hip_runtime.h>
#include <math.h>

// Match the numpy/JAX reference op-for-op: no FMA contraction anywhere in
// the expressions that feed discrete decisions (alpha values, voxel trunc).
#pragma clang fp contract(off)

#define BATCH 8
static constexpr int HH = 200, WW = 200;
static constexpr int NRAY = HH * WW;          // 40000
static constexpr int NG   = NRAY / 64;        // 625 wave-groups (64 rays each)
static constexpr int MAIN_BLOCKS = 2048;      // 8192 wave slots = 1 full round
static constexpr int KSCALE = 7552;           // 8192 - 640: floor+min-1 bumps <= 8192
static constexpr int RBLK = (NRAY + 255) / 256;  // 157

// ws float-index layout
static constexpr int WS_SDD0 = 0;
static constexpr int WS_SDD1 = NRAY;
static constexpr int WS_SDD2 = 2 * NRAY;
static constexpr int WS_AMIN = 3 * NRAY;
static constexpr int WS_AMAX = 4 * NRAY;
static constexpr int WS_NORM = 5 * NRAY;
static constexpr int WS_CNT  = 6 * NRAY;          // int: per-ray crossing count
static constexpr int WS_UNI  = 7 * NRAY;          // src0..2, spn0..2
static constexpr int WS_GMAX = 7 * NRAY + 8;      // int[NG]
static constexpr int WS_BASE = 7 * NRAY + 8 + NG; // int[NG+1] prefix
static constexpr int WS_PART = 281280;            // padded; 8192*64 floats
static constexpr size_t WS_BYTES = (size_t)(WS_PART + 8192 * 64) * 4;

__device__ __forceinline__ float alpha_of(float k, float sp, float src, float sdd) {
    return (k * sp - src) / sdd;   // reference: (k*spacing - src)/sdd, mul-sub-div
}

// Traversal pointer at threshold X: first crossing (traversal order) with
// alpha > X. Seeded analytically, fixed up with the exact reference divide.
__device__ __forceinline__ int seed_ptr(float X, float spv, float sr, float sd, bool pos) {
    const float kf = (X * sd + sr) / spv;
    int kk;
    if (pos) {
        kk = (int)floorf(kf) + 1;
        kk = kk < 0 ? 0 : (kk > 257 ? 257 : kk);
        while (kk > 0    && alpha_of((float)(kk-1), spv, sr, sd) >  X) --kk;
        while (kk <= 256 && alpha_of((float)kk,     spv, sr, sd) <= X) ++kk;
    } else {
        kk = (int)ceilf(kf) - 1;
        kk = kk > 256 ? 256 : (kk < -1 ? -1 : kk);
        while (kk < 256 && alpha_of((float)(kk+1), spv, sr, sd) >  X) ++kk;
        while (kk >= 0  && alpha_of((float)kk,     spv, sr, sd) <= X) --kk;
    }
    return kk;
}

// One interval: q = min of the 3 exact next-crossing alphas; sample voxel at
// midpoint; advance the argmin axis with the EXACT reference divide (every tM
// is always reference bits — zero accumulated drift; R6-verified advance).
#define GEN_INTERVAL(stepv, addrv)                                       \
    {   const float q = fminf(fminf(tM0, tM1), tM2);                     \
        stepv = q - prev;                                                \
        const float amid = 0.5f * (prev + q);                            \
        const float p0 = src0 + amid * sdd0;                             \
        const float p1 = src1 + amid * sdd1;                             \
        const float p2 = src2 + amid * sdd2;                             \
        float f0, f1, f2;                                                \
        if (UNIT) { f0 = p0; f1 = p1; f2 = p2; }                         \
        else      { f0 = p0 / spn0; f1 = p1 / spn1; f2 = p2 / spn2; }    \
        f0 = fminf(fmaxf(f0, 0.0f), 255.0f);                             \
        f1 = fminf(fmaxf(f1, 0.0f), 255.0f);                             \
        f2 = fminf(fmaxf(f2, 0.0f), 255.0f);                             \
        const int i0 = (int)f0, i1 = (int)f1, i2 = (int)f2;              \
        addrv = ((((255 ^ i0) << 8) + i1) << 8) + i2;                    \
        prev = q;                                                        \
        const bool m0 = (tM0 == q);                                      \
        const bool m1 = !m0 && (tM1 == q);                               \
        const float kf_s  = m0 ? kf0  : (m1 ? kf1  : kf2);               \
        const float kst_s = m0 ? kst0 : (m1 ? kst1 : kst2);              \
        const float sr_s  = m0 ? src0 : (m1 ? src1 : src2);              \
        const float sd_s  = m0 ? sdd0 : (m1 ? sdd1 : sdd2);              \
        const float nk = kf_s + kst_s;                                   \
        float al;                                                        \
        if (UNIT) { al = (nk - sr_s) / sd_s; }                           \
        else { const float sp_s = m0 ? spn0 : (m1 ? spn1 : spn2);        \
               al = (nk * sp_s - sr_s) / sd_s; }                         \
        const float nv = (nk >= 0.0f && nk <= 256.0f) ? al : INFINITY;   \
        if (m0)      { kf0 = nk; tM0 = nv; }                             \
        else if (m1) { kf1 = nk; tM1 = nv; }                             \
        else         { kf2 = nk; tM2 = nv; }                             \
    }

// Count-based merge, batch-8 (loads generated ahead of consumption).
template<bool UNIT>
__device__ __forceinline__ float merge_loop(
    const float* __restrict__ vol, int trip, float prev,
    float kf0, float kf1, float kf2,
    float kst0, float kst1, float kst2,
    float tM0, float tM1, float tM2,
    float src0, float src1, float src2,
    float spn0, float spn1, float spn2,
    float sdd0, float sdd1, float sdd2)
{
    float acc = 0.0f;
    int n = trip;
    while (n >= BATCH) {
        float stepv[BATCH], vox[BATCH];
        int addr[BATCH];
        #pragma unroll
        for (int i = 0; i < BATCH; ++i) {
            GEN_INTERVAL(stepv[i], addr[i])
            vox[i] = vol[addr[i]];
        }
        #pragma unroll
        for (int i = 0; i < BATCH; ++i)
            acc = fmaf(stepv[i], vox[i], acc);
        n -= BATCH;
    }
    while (n > 0) {
        float stepv;
        int addr;
        GEN_INTERVAL(stepv, addr)
        acc = fmaf(stepv, vol[addr], acc);
        --n;
    }
    return acc;
}

// Shared per-segment body: seeds (exact) + merge; returns partial sum.
__device__ __forceinline__ float trace_window(
    const float* __restrict__ vol,
    float amin, float amax, int s, int nseg,
    float src0, float src1, float src2,
    float spn0, float spn1, float spn2,
    float sdd0, float sdd1, float sdd2, bool unit)
{
    const float blo = (s == 0) ? amin
                    : amin + (amax - amin) * ((float)s / (float)nseg);
    const float bhi = (s == nseg - 1) ? amax
                    : amin + (amax - amin) * ((float)(s + 1) / (float)nseg);

    const float sddv[3] = { sdd0, sdd1, sdd2 };
    const float srcv[3] = { src0, src1, src2 };
    const float spnv[3] = { spn0, spn1, spn2 };
    float kf[3], kst[3], tM[3];
    float prev = -INFINITY;
    int trip = 0;

    for (int a = 0; a < 3; ++a) {
        const float sd = sddv[a], sr = srcv[a], spv = spnv[a];
        const bool pos = sd > 0.0f;
        kst[a] = pos ? 1.0f : -1.0f;
        const int ks = seed_ptr(blo, spv, sr, sd, pos);
        const int ke = seed_ptr(bhi, spv, sr, sd, pos);
        int cnt;
        if (pos) {
            cnt = ke - ks;
            if (ks - 1 >= 0) {
                const float ap = alpha_of((float)(ks-1), spv, sr, sd);
                if (ap >= amin && ap > prev) prev = ap;
            }
            tM[a] = (ks <= 256) ? alpha_of((float)ks, spv, sr, sd) : INFINITY;
        } else {
            cnt = ks - ke;
            if (ks + 1 <= 256) {
                const float ap = alpha_of((float)(ks+1), spv, sr, sd);
                if (ap >= amin && ap > prev) prev = ap;
            }
            tM[a] = (ks >= 0) ? alpha_of((float)ks, spv, sr, sd) : INFINITY;
        }
        if (cnt < 0) cnt = 0;
        trip += cnt;
        kf[a] = (float)ks;
    }

    if (unit)
        return merge_loop<true >(vol, trip, prev, kf[0], kf[1], kf[2],
                                 kst[0], kst[1], kst[2], tM[0], tM[1], tM[2],
                                 src0, src1, src2, spn0, spn1, spn2,
                                 sdd0, sdd1, sdd2);
    else
        return merge_loop<false>(vol, trip, prev, kf[0], kf[1], kf[2],
                                 kst[0], kst[1], kst[2], tM[0], tM[1], tM[2],
                                 src0, src1, src2, spn0, spn1, spn2,
                                 sdd0, sdd1, sdd2);
}

// ---------------- A: per-ray geometry + total crossing count ---------------
__global__ __launch_bounds__(256)
void drr_pre(const float* __restrict__ spacing,
             const float* __restrict__ sdrP,  const float* __restrict__ thetaP,
             const float* __restrict__ phiP,  const float* __restrict__ gammaP,
             const float* __restrict__ bxP,   const float* __restrict__ byP,
             const float* __restrict__ bzP,   float* __restrict__ ws)
{
    const int rid = blockIdx.x * blockDim.x + threadIdx.x;
    if (rid >= NRAY) return;
    const int it = rid % HH, is = rid / HH;

    const float sdr = sdrP[0];
    const float th = thetaP[0], ph = phiP[0], ga = gammaP[0];
    const float ct = cosf(th), st = sinf(th);
    const float cp = cosf(ph), sp = sinf(ph);
    const float cg = cosf(ga), sg = sinf(ga);

    const float rot[3][3] = {
        { ct*cp, ct*sp*sg - st*cg, ct*sp*cg + st*sg },
        { st*cp, st*sp*sg + ct*cg, st*sp*cg - ct*sg },
        { -sp,   cp*sg,            cp*cg            }
    };

    float u[3], v[3], source[3], trans[3], src[3], spn[3];
    trans[0] = bxP[0]; trans[1] = byP[0]; trans[2] = bzP[0];
    for (int a = 0; a < 3; ++a) {
        source[a] = sdr * rot[a][0];
        u[a] = (sdr * rot[a][1]) / sdr;
        v[a] = (sdr * rot[a][2]) / sdr;
        src[a] = source[a] + trans[a];
        spn[a] = spacing[a];
    }

    const float tc = (float)(it - HH/2 + 1) * 2.0f;   // DELX
    const float sc = (float)(is - WW/2 + 1) * 2.0f;   // DELY

    float sdd[3];
    float nrm2 = 0.0f;
    for (int a = 0; a < 3; ++a) {
        float tg = tc * u[a] + sc * v[a];
        tg = tg - source[a];
        tg = tg + trans[a];
        float dd = (tg - src[a]) + 1e-8f;  // sdd = tgt - src + EPS
        sdd[a] = dd;
        nrm2 = nrm2 + dd * dd;
    }

    float amin = -INFINITY, amax = INFINITY;
    for (int a = 0; a < 3; ++a) {
        float a0 = (0.0f - src[a]) / sdd[a];
        float a1 = (256.0f * spn[a] - src[a]) / sdd[a];
        amin = fmaxf(amin, fminf(a0, a1));
        amax = fminf(amax, fmaxf(a0, a1));
    }

    ws[WS_SDD0 + rid] = sdd[0];
    ws[WS_SDD1 + rid] = sdd[1];
    ws[WS_SDD2 + rid] = sdd[2];
    ws[WS_AMIN + rid] = amin;
    ws[WS_AMAX + rid] = amax;
    ws[WS_NORM + rid] = sqrtf(nrm2);

    int cnt = 0;
    if (amax > amin) {
        for (int a = 0; a < 3; ++a) {
            const float sd = sdd[a], sr = src[a], spv = spn[a];
            const bool pos = sd > 0.0f;
            const int ks = seed_ptr(amin, spv, sr, sd, pos);
            const int ke = seed_ptr(amax, spv, sr, sd, pos);
            int c = pos ? (ke - ks) : (ks - ke);
            if (c > 0) cnt += c;
        }
    }
    ((int*)ws)[WS_CNT + rid] = cnt;

    if (rid == 0) {   // src and spn are ray-independent
        ws[WS_UNI + 0] = src[0]; ws[WS_UNI + 1] = src[1]; ws[WS_UNI + 2] = src[2];
        ws[WS_UNI + 3] = spn[0]; ws[WS_UNI + 4] = spn[1]; ws[WS_UNI + 5] = spn[2];
    }
}

// ---------------- B: per-group max count ------------------------------------
__global__ __launch_bounds__(256)
void drr_gmax(float* __restrict__ ws)
{
    const int g = blockIdx.x * blockDim.x + threadIdx.x;
    if (g >= NG) return;
    const int* wsi = (const int*)ws;
    int m = 0;
    for (int l = 0; l < 64; ++l) {
        const int c = wsi[WS_CNT + (g << 6) + l];
        m = c > m ? c : m;
    }
    ((int*)ws)[WS_GMAX + g] = m;
}

// ---------------- C: plan — n_g proportional to max count, prefix sum -------
__global__ __launch_bounds__(1024)
void drr_plan(float* __restrict__ ws)
{
    __shared__ int sh[1024];
    const int i = threadIdx.x;
    int* wsi = (int*)ws;
    const int v = (i < NG) ? wsi[WS_GMAX + i] : 0;
    sh[i] = v;
    __syncthreads();
    for (int off = 512; off > 0; off >>= 1) {
        if (i < off) sh[i] += sh[i + off];
        __syncthreads();
    }
    const int total = sh[0];
    __syncthreads();
    int n = 0;
    if (i < NG) {
        n = (total > 0) ? (int)(((long long)KSCALE * v) / total) : 1;
        if (n < 1) n = 1;
    }
    sh[i] = n;
    __syncthreads();
    for (int off = 1; off < 1024; off <<= 1) {
        const int t = (i >= off) ? sh[i - off] : 0;
        __syncthreads();
        sh[i] += t;
        __syncthreads();
    }
    if (i < NG) wsi[WS_BASE + i + 1] = sh[i];
    if (i == 0) wsi[WS_BASE] = 0;
}

// ---------------- D: main — one balanced work item per wave -----------------
__global__ __launch_bounds__(256)
void drr_main(const float* __restrict__ vol, float* __restrict__ ws)
{
    const int* wsi = (const int*)ws;
    const int lane = threadIdx.x & 63;
    // XCD-chunked wave id: blocks round-robin XCDs; each XCD owns a contiguous
    // 1024-wave range (contiguous detector band -> L2 locality).
    const int w = ((blockIdx.x & 7) << 10) + ((blockIdx.x >> 3) << 2)
                + (threadIdx.x >> 6);
    const int total = wsi[WS_BASE + NG];
    if (w >= total) return;      // idle slots (<= ~8% by construction)

    int lo = 0, hi = NG;         // find g: base[g] <= w < base[g+1]
    while (hi - lo > 1) {
        const int mid = (lo + hi) >> 1;
        if (wsi[WS_BASE + mid] <= w) lo = mid; else hi = mid;
    }
    const int g    = lo;
    const int base = wsi[WS_BASE + g];
    const int nseg = wsi[WS_BASE + g + 1] - base;
    const int s    = w - base;
    const int rid  = (g << 6) + lane;

    const float sdd0 = ws[WS_SDD0 + rid];
    const float sdd1 = ws[WS_SDD1 + rid];
    const float sdd2 = ws[WS_SDD2 + rid];
    const float amin = ws[WS_AMIN + rid];
    const float amax = ws[WS_AMAX + rid];
    const float src0 = ws[WS_UNI + 0], src1 = ws[WS_UNI + 1], src2 = ws[WS_UNI + 2];
    const float spn0 = ws[WS_UNI + 3], spn1 = ws[WS_UNI + 4], spn2 = ws[WS_UNI + 5];
    const bool unit = (spn0 == 1.0f) & (spn1 == 1.0f) & (spn2 == 1.0f);

    float acc = 0.0f;
    if (amax > amin)
        acc = trace_window(vol, amin, amax, s, nseg,
                           src0, src1, src2, spn0, spn1, spn2,
                           sdd0, sdd1, sdd2, unit);

    ws[WS_PART + w * 64 + lane] = acc;   // coalesced, no atomic
}

// ---------------- E: reduce partials in fixed s order, apply norm -----------
__global__ __launch_bounds__(256)
void drr_fin(const float* __restrict__ ws, float* __restrict__ out)
{
    const int rid = blockIdx.x * blockDim.x + threadIdx.x;
    if (rid >= NRAY) return;
    const int* wsi = (const int*)ws;
    const int g    = rid >> 6;
    const int lane = rid & 63;
    const int base = wsi[WS_BASE + g];
    const int nseg = wsi[WS_BASE + g + 1] - base;
    float sum = 0.0f;
    for (int s = 0; s < nseg; ++s)
        sum = sum + ws[WS_PART + (base + s) * 64 + lane];   // fixed order
    const int it = rid % HH, is = rid / HH;
    out[it * WW + is] = sum * ws[WS_NORM + rid];
}

// ---------------- fallback: monolithic atomic path (R12-equivalent) ---------
__global__ __launch_bounds__(256)
void drr_mono(const float* __restrict__ vol,
              const float* __restrict__ spacing,
              const float* __restrict__ sdrP,  const float* __restrict__ thetaP,
              const float* __restrict__ phiP,  const float* __restrict__ gammaP,
              const float* __restrict__ bxP,   const float* __restrict__ byP,
              const float* __restrict__ bzP,   float* __restrict__ out)
{
    const int tid = blockIdx.x * blockDim.x + threadIdx.x;
    if (tid >= NRAY * 13) return;
    const int seg = tid / NRAY;
    const int rid = tid - seg * NRAY;
    const int it = rid % HH, is = rid / HH;

    const float sdr = sdrP[0];
    const float th = thetaP[0], ph = phiP[0], ga = gammaP[0];
    const float ct = cosf(th), st = sinf(th);
    const float cp = cosf(ph), sp = sinf(ph);
    const float cg = cosf(ga), sg = sinf(ga);
    const float rot[3][3] = {
        { ct*cp, ct*sp*sg - st*cg, ct*sp*cg + st*sg },
        { st*cp, st*sp*sg + ct*cg, st*sp*cg - ct*sg },
        { -sp,   cp*sg,            cp*cg            }
    };
    float u[3], v[3], source[3], trans[3], src[3], spn[3];
    trans[0] = bxP[0]; trans[1] = byP[0]; trans[2] = bzP[0];
    for (int a = 0; a < 3; ++a) {
        source[a] = sdr * rot[a][0];
        u[a] = (sdr * rot[a][1]) / sdr;
        v[a] = (sdr * rot[a][2]) / sdr;
        src[a] = source[a] + trans[a];
        spn[a] = spacing[a];
    }
    const float tc = (float)(it - HH/2 + 1) * 2.0f;
    const float sc = (float)(is - WW/2 + 1) * 2.0f;
    float sdd[3]; float nrm2 = 0.0f;
    for (int a = 0; a < 3; ++a) {
        float tg = tc * u[a] + sc * v[a];
        tg = tg - source[a];
        tg = tg + trans[a];
        float dd = (tg - src[a]) + 1e-8f;
        sdd[a] = dd;
        nrm2 = nrm2 + dd * dd;
    }
    const bool unit = (spn[0] == 1.0f) & (spn[1] == 1.0f) & (spn[2] == 1.0f);
    float amin = -INFINITY, amax = INFINITY;
    for (int a = 0; a < 3; ++a) {
        float a0 = (0.0f - src[a]) / sdd[a];
        float a1 = (256.0f * spn[a] - src[a]) / sdd[a];
        amin = fmaxf(amin, fminf(a0, a1));
        amax = fminf(amax, fmaxf(a0, a1));
    }
    float acc = 0.0f;
    if (amax > amin)
        acc = trace_window(vol, amin, amax, seg, 13,
                           src[0], src[1], src[2], spn[0], spn[1], spn[2],
                           sdd[0], sdd[1], sdd[2], unit);
    atomicAdd(&out[it * WW + is], acc * sqrtf(nrm2));
}

extern "C" void kernel_launch(void* const* d_in, const int* in_sizes, int n_in,
                              void* d_out, int out_size, void* d_ws, size_t ws_size,
                              hipStream_t stream)
{
    const float* vol     = (const float*)d_in[0];
    const float* spacing = (const float*)d_in[1];
    const float* sdr     = (const float*)d_in[2];
    const float* theta   = (const float*)d_in[3];
    const float* phi     = (const float*)d_in[4];
    const float* gamma   = (const float*)d_in[5];
    const float* bx      = (const float*)d_in[6];
    const float* by      = (const float*)d_in[7];
    const float* bz      = (const float*)d_in[8];
    float* out = (float*)d_out;

    if (ws_size >= WS_BYTES) {
        float* ws = (float*)d_ws;
        drr_pre <<<RBLK, 256, 0, stream>>>(spacing, sdr, theta, phi, gamma,
                                           bx, by, bz, ws);
        drr_gmax<<<(NG + 255) / 256, 256, 0, stream>>>(ws);
        drr_plan<<<1, 1024, 0, stream>>>(ws);
        drr_main<<<MAIN_BLOCKS, 256, 0, stream>>>(vol, ws);
        drr_fin <<<RBLK, 256, 0, stream>>>(ws, out);
    } else {
        hipMemsetAsync(out, 0, (size_t)out_size * sizeof(float), stream);
        drr_mono<<<(NRAY * 13 + 255) / 256, 256, 0, stream>>>(
            vol, spacing, sdr, theta, phi, gamma, bx, by, bz, out);
    }
}

// Round 15
// 52.754 us; speedup vs baseline: 1.6363x; 1.6363x over previous
//
#include <hip/hip_runtime.h>
#include <math.h>

// Match the numpy/JAX reference op-for-op: no FMA contraction anywhere in
// the expressions that feed discrete decisions (alpha values, voxel trunc).
#pragma clang fp contract(off)

#define SPLIT 13
#define BATCH 8
static constexpr int HH = 200, WW = 200;
static constexpr int NRAY = HH * WW;
static constexpr int RBLK = 157;            // ceil(NRAY/256)
static constexpr int NWG  = RBLK * SPLIT;   // 2041 blocks

// d_ws float layout
static constexpr int WS_SDD0 = 0;
static constexpr int WS_SDD1 = NRAY;
static constexpr int WS_SDD2 = 2 * NRAY;
static constexpr int WS_AMIN = 3 * NRAY;
static constexpr int WS_AMAX = 4 * NRAY;
static constexpr int WS_NORM = 5 * NRAY;
static constexpr int WS_UNI  = 6 * NRAY;          // src0..2, spn0..2
static constexpr int WS_PART = 6 * NRAY + 8;      // SPLIT x NRAY partials
static constexpr size_t WS_BYTES = (size_t)(WS_PART + SPLIT * NRAY) * 4;

__device__ __forceinline__ float alpha_of(float k, float sp, float src, float sdd) {
    return (k * sp - src) / sdd;   // reference: (k*spacing - src)/sdd, mul-sub-div
}

// Traversal pointer at threshold X: first crossing (traversal order) with
// alpha > X. Seeded analytically, fixed up with the exact reference divide.
__device__ __forceinline__ int seed_ptr(float X, float spv, float sr, float sd, bool pos) {
    const float kf = (X * sd + sr) / spv;
    int kk;
    if (pos) {
        kk = (int)floorf(kf) + 1;
        kk = kk < 0 ? 0 : (kk > 257 ? 257 : kk);
        while (kk > 0    && alpha_of((float)(kk-1), spv, sr, sd) >  X) --kk;
        while (kk <= 256 && alpha_of((float)kk,     spv, sr, sd) <= X) ++kk;
    } else {
        kk = (int)ceilf(kf) - 1;
        kk = kk > 256 ? 256 : (kk < -1 ? -1 : kk);
        while (kk < 256 && alpha_of((float)(kk+1), spv, sr, sd) >  X) ++kk;
        while (kk >= 0  && alpha_of((float)kk,     spv, sr, sd) <= X) --kk;
    }
    return kk;
}

// Generate one interval's (step, byte-offset) from the tM recurrence and
// advance. Identical float ops to rounds 8-13 (bit-identical stream).
#define GEN_INTERVAL(stepv, offv)                                        \
    {   const float q = fminf(fminf(tM0, tM1), tM2);                     \
        stepv = q - prev;                                                \
        const float amid = 0.5f * (prev + q);                            \
        const float p0 = src0 + amid * sdd0;                             \
        const float p1 = src1 + amid * sdd1;                             \
        const float p2 = src2 + amid * sdd2;                             \
        float f0, f1, f2;                                                \
        if (UNIT) { f0 = p0; f1 = p1; f2 = p2; }                         \
        else      { f0 = p0 / spn0; f1 = p1 / spn1; f2 = p2 / spn2; }    \
        f0 = fminf(fmaxf(f0, 0.0f), 255.0f);                             \
        f1 = fminf(fmaxf(f1, 0.0f), 255.0f);                             \
        f2 = fminf(fmaxf(f2, 0.0f), 255.0f);                             \
        const int i0 = (int)f0, i1 = (int)f1, i2 = (int)f2;              \
        offv = (unsigned)(((((255 ^ i0) << 8) + i1) << 8) + i2) << 2;    \
        prev = q;                                                        \
        const bool m0 = (tM0 == q);                                      \
        const bool m1 = !m0 && (tM1 == q);                               \
        const bool m2 = !(m0 || m1);                                     \
        tM0 = m0 ? tM0 + dl0 : tM0;                                      \
        tM1 = m1 ? tM1 + dl1 : tM1;                                      \
        tM2 = m2 ? tM2 + dl2 : tM2; }

// Count-based merge with guaranteed MLP (volatile asm loads + counted wait).
template<bool UNIT>
__device__ __forceinline__ float merge_loop(
    const float* __restrict__ vol, int trip, float prev,
    float tM0, float tM1, float tM2,
    float dl0, float dl1, float dl2,
    float src0, float src1, float src2,
    float spn0, float spn1, float spn2,
    float sdd0, float sdd1, float sdd2)
{
    float acc = 0.0f;
    int n = trip;
    while (n >= BATCH) {
        float stepv[BATCH], vox[BATCH];
        unsigned off[BATCH];
        #pragma unroll
        for (int i = 0; i < BATCH; ++i) {
            GEN_INTERVAL(stepv[i], off[i])
            asm volatile("global_load_dword %0, %1, %2"
                         : "=v"(vox[i])
                         : "v"(off[i]), "s"(vol));
        }
        asm volatile("s_waitcnt vmcnt(0)");
        __builtin_amdgcn_sched_barrier(0);
        #pragma unroll
        for (int i = 0; i < BATCH; ++i)
            acc = fmaf(stepv[i], vox[i], acc);
        n -= BATCH;
    }
    while (n > 0) {
        float stepv;
        unsigned off;
        GEN_INTERVAL(stepv, off)
        const float vox = vol[off >> 2];
        acc = fmaf(stepv, vox, acc);
        --n;
    }
    return acc;
}

// ---------------- A: per-ray geometry (exactly the R13 pre-kernel) ----------
__global__ __launch_bounds__(256)
void drr_pre(const float* __restrict__ spacing,
             const float* __restrict__ sdrP,  const float* __restrict__ thetaP,
             const float* __restrict__ phiP,  const float* __restrict__ gammaP,
             const float* __restrict__ bxP,   const float* __restrict__ byP,
             const float* __restrict__ bzP,   float* __restrict__ ws)
{
    const int rid = blockIdx.x * blockDim.x + threadIdx.x;
    if (rid >= NRAY) return;
    const int it = rid % HH, is = rid / HH;

    const float sdr = sdrP[0];
    const float th = thetaP[0], ph = phiP[0], ga = gammaP[0];
    const float ct = cosf(th), st = sinf(th);
    const float cp = cosf(ph), sp = sinf(ph);
    const float cg = cosf(ga), sg = sinf(ga);

    const float rot[3][3] = {
        { ct*cp, ct*sp*sg - st*cg, ct*sp*cg + st*sg },
        { st*cp, st*sp*sg + ct*cg, st*sp*cg - ct*sg },
        { -sp,   cp*sg,            cp*cg            }
    };

    float u[3], v[3], source[3], trans[3], src[3], spn[3];
    trans[0] = bxP[0]; trans[1] = byP[0]; trans[2] = bzP[0];
    for (int a = 0; a < 3; ++a) {
        source[a] = sdr * rot[a][0];
        u[a] = (sdr * rot[a][1]) / sdr;
        v[a] = (sdr * rot[a][2]) / sdr;
        src[a] = source[a] + trans[a];
        spn[a] = spacing[a];
    }

    const float tc = (float)(it - HH/2 + 1) * 2.0f;   // DELX
    const float sc = (float)(is - WW/2 + 1) * 2.0f;   // DELY

    float sdd[3];
    float nrm2 = 0.0f;
    for (int a = 0; a < 3; ++a) {
        float tg = tc * u[a] + sc * v[a];
        tg = tg - source[a];
        tg = tg + trans[a];
        float dd = (tg - src[a]) + 1e-8f;  // sdd = tgt - src + EPS
        sdd[a] = dd;
        nrm2 = nrm2 + dd * dd;
    }

    float amin = -INFINITY, amax = INFINITY;
    for (int a = 0; a < 3; ++a) {
        float a0 = (0.0f - src[a]) / sdd[a];
        float a1 = (256.0f * spn[a] - src[a]) / sdd[a];
        amin = fmaxf(amin, fminf(a0, a1));
        amax = fminf(amax, fmaxf(a0, a1));
    }

    ws[WS_SDD0 + rid] = sdd[0];
    ws[WS_SDD1 + rid] = sdd[1];
    ws[WS_SDD2 + rid] = sdd[2];
    ws[WS_AMIN + rid] = amin;
    ws[WS_AMAX + rid] = amax;
    ws[WS_NORM + rid] = sqrtf(nrm2);
    if (rid == 0) {   // src and spn are ray-independent
        ws[WS_UNI + 0] = src[0]; ws[WS_UNI + 1] = src[1]; ws[WS_UNI + 2] = src[2];
        ws[WS_UNI + 3] = spn[0]; ws[WS_UNI + 4] = spn[1]; ws[WS_UNI + 5] = spn[2];
    }
}

// ---------------- B: merge (single lever vs R13: ridBlk-fastest in XCD) -----
__global__ __launch_bounds__(256)
void drr_main(const float* __restrict__ vol,
              float* __restrict__ ws)
{
    // XCD-aware bijective swizzle; intra-XCD order FLIPPED to ridBlk-fastest:
    // an XCD's 255 consecutive blocks now cover the whole detector at ~1.6
    // alpha-segments (working set ~8 MB) instead of a 25-column band over all
    // 13 segments (~13 MB).
    const int lin = blockIdx.x;
    const int xcd = lin & 7;
    const int pos = lin >> 3;
    const int swz = (xcd == 0) ? pos : (256 + (xcd - 1) * 255 + pos);
    const int seg    = swz / RBLK;            // <- flipped (was swz % SPLIT)
    const int ridBlk = swz - seg * RBLK;      // <- flipped (was swz / SPLIT)

    const int rid = ridBlk * 256 + threadIdx.x;
    if (rid >= NRAY) return;

    const float sdd0 = ws[WS_SDD0 + rid];
    const float sdd1 = ws[WS_SDD1 + rid];
    const float sdd2 = ws[WS_SDD2 + rid];
    const float amin = ws[WS_AMIN + rid];
    const float amax = ws[WS_AMAX + rid];
    const float src0 = ws[WS_UNI + 0], src1 = ws[WS_UNI + 1], src2 = ws[WS_UNI + 2];
    const float spn0 = ws[WS_UNI + 3], spn1 = ws[WS_UNI + 4], spn2 = ws[WS_UNI + 5];
    const bool unit = (spn0 == 1.0f) & (spn1 == 1.0f) & (spn2 == 1.0f);

    float acc = 0.0f;
    if (amax > amin) {
        const float blo = (seg == 0) ? amin
                        : amin + (amax - amin) * ((float)seg / (float)SPLIT);
        const float bhi = (seg == SPLIT - 1) ? amax
                        : amin + (amax - amin) * ((float)(seg + 1) / (float)SPLIT);

        const float sddv[3] = { sdd0, sdd1, sdd2 };
        const float srcv[3] = { src0, src1, src2 };
        const float spnv[3] = { spn0, spn1, spn2 };
        float tM[3], dl[3];
        float prev = -INFINITY;
        int trip = 0;

        for (int a = 0; a < 3; ++a) {
            const float sd = sddv[a], sr = srcv[a], spv = spnv[a];
            const bool pos2 = sd > 0.0f;
            const int ks = seed_ptr(blo, spv, sr, sd, pos2);
            const int ke = seed_ptr(bhi, spv, sr, sd, pos2);
            int cnt;
            if (pos2) {
                cnt = ke - ks;
                if (ks - 1 >= 0) {
                    const float ap = alpha_of((float)(ks-1), spv, sr, sd);
                    if (ap >= amin && ap > prev) prev = ap;
                }
                tM[a] = (ks <= 256) ? alpha_of((float)ks, spv, sr, sd) : INFINITY;
            } else {
                cnt = ks - ke;
                if (ks + 1 <= 256) {
                    const float ap = alpha_of((float)(ks+1), spv, sr, sd);
                    if (ap >= amin && ap > prev) prev = ap;
                }
                tM[a] = (ks >= 0) ? alpha_of((float)ks, spv, sr, sd) : INFINITY;
            }
            if (cnt < 0) cnt = 0;
            trip += cnt;
            dl[a] = fabsf(spv / sd);
        }

        if (unit) {
            acc = merge_loop<true >(vol, trip, prev, tM[0], tM[1], tM[2],
                                    dl[0], dl[1], dl[2], src0, src1, src2,
                                    spn0, spn1, spn2, sdd0, sdd1, sdd2);
        } else {
            acc = merge_loop<false>(vol, trip, prev, tM[0], tM[1], tM[2],
                                    dl[0], dl[1], dl[2], src0, src1, src2,
                                    spn0, spn1, spn2, sdd0, sdd1, sdd2);
        }
    }

    // plain coalesced store — no atomic, no memset dependency
    ws[WS_PART + seg * NRAY + rid] = acc;
}

// ---------------- C: reduce partials, apply norm, write out ----------------
__global__ __launch_bounds__(256)
void drr_fin(const float* __restrict__ ws, float* __restrict__ out)
{
    const int rid = blockIdx.x * blockDim.x + threadIdx.x;
    if (rid >= NRAY) return;
    float s = 0.0f;
    #pragma unroll
    for (int seg = 0; seg < SPLIT; ++seg)
        s = s + ws[WS_PART + seg * NRAY + rid];   // fixed seg order
    const int it = rid % HH, is = rid / HH;
    out[it * WW + is] = s * ws[WS_NORM + rid];
}

// ---------------- fallback: round-12 monolithic atomic path ----------------
__global__ __launch_bounds__(256)
void drr_mono(const float* __restrict__ vol,
              const float* __restrict__ spacing,
              const float* __restrict__ sdrP,  const float* __restrict__ thetaP,
              const float* __restrict__ phiP,  const float* __restrict__ gammaP,
              const float* __restrict__ bxP,   const float* __restrict__ byP,
              const float* __restrict__ bzP,   float* __restrict__ out)
{
    const int lin = blockIdx.x;
    const int xcd = lin & 7;
    const int pos = lin >> 3;
    const int swz = (xcd == 0) ? pos : (256 + (xcd - 1) * 255 + pos);
    const int seg    = swz / RBLK;
    const int ridBlk = swz - seg * RBLK;
    const int rid = ridBlk * 256 + threadIdx.x;
    if (rid >= NRAY) return;
    const int it = rid % HH, is = rid / HH;

    const float sdr = sdrP[0];
    const float th = thetaP[0], ph = phiP[0], ga = gammaP[0];
    const float ct = cosf(th), st = sinf(th);
    const float cp = cosf(ph), sp = sinf(ph);
    const float cg = cosf(ga), sg = sinf(ga);
    const float rot[3][3] = {
        { ct*cp, ct*sp*sg - st*cg, ct*sp*cg + st*sg },
        { st*cp, st*sp*sg + ct*cg, st*sp*cg - ct*sg },
        { -sp,   cp*sg,            cp*cg            }
    };
    float u[3], v[3], source[3], trans[3], src[3], spn[3];
    trans[0] = bxP[0]; trans[1] = byP[0]; trans[2] = bzP[0];
    for (int a = 0; a < 3; ++a) {
        source[a] = sdr * rot[a][0];
        u[a] = (sdr * rot[a][1]) / sdr;
        v[a] = (sdr * rot[a][2]) / sdr;
        src[a] = source[a] + trans[a];
        spn[a] = spacing[a];
    }
    const float tc = (float)(it - HH/2 + 1) * 2.0f;
    const float sc = (float)(is - WW/2 + 1) * 2.0f;
    float sdd[3]; float nrm2 = 0.0f;
    for (int a = 0; a < 3; ++a) {
        float tg = tc * u[a] + sc * v[a];
        tg = tg - source[a];
        tg = tg + trans[a];
        float dd = (tg - src[a]) + 1e-8f;
        sdd[a] = dd;
        nrm2 = nrm2 + dd * dd;
    }
    const bool unit = (spn[0] == 1.0f) & (spn[1] == 1.0f) & (spn[2] == 1.0f);
    float amin = -INFINITY, amax = INFINITY;
    for (int a = 0; a < 3; ++a) {
        float a0 = (0.0f - src[a]) / sdd[a];
        float a1 = (256.0f * spn[a] - src[a]) / sdd[a];
        amin = fmaxf(amin, fminf(a0, a1));
        amax = fminf(amax, fmaxf(a0, a1));
    }
    float acc = 0.0f;
    if (amax > amin) {
        const float blo = (seg == 0) ? amin
                        : amin + (amax - amin) * ((float)seg / (float)SPLIT);
        const float bhi = (seg == SPLIT - 1) ? amax
                        : amin + (amax - amin) * ((float)(seg + 1) / (float)SPLIT);
        float tM[3], dl[3];
        float prev = -INFINITY;
        int trip = 0;
        for (int a = 0; a < 3; ++a) {
            const float sd = sdd[a], sr = src[a], spv = spn[a];
            const bool pos2 = sd > 0.0f;
            const int ks = seed_ptr(blo, spv, sr, sd, pos2);
            const int ke = seed_ptr(bhi, spv, sr, sd, pos2);
            int cnt;
            if (pos2) {
                cnt = ke - ks;
                if (ks - 1 >= 0) {
                    const float ap = alpha_of((float)(ks-1), spv, sr, sd);
                    if (ap >= amin && ap > prev) prev = ap;
                }
                tM[a] = (ks <= 256) ? alpha_of((float)ks, spv, sr, sd) : INFINITY;
            } else {
                cnt = ks - ke;
                if (ks + 1 <= 256) {
                    const float ap = alpha_of((float)(ks+1), spv, sr, sd);
                    if (ap >= amin && ap > prev) prev = ap;
                }
                tM[a] = (ks >= 0) ? alpha_of((float)ks, spv, sr, sd) : INFINITY;
            }
            if (cnt < 0) cnt = 0;
            trip += cnt;
            dl[a] = fabsf(spv / sd);
        }
        if (unit) {
            acc = merge_loop<true >(vol, trip, prev, tM[0], tM[1], tM[2],
                                    dl[0], dl[1], dl[2], src[0], src[1], src[2],
                                    spn[0], spn[1], spn[2], sdd[0], sdd[1], sdd[2]);
        } else {
            acc = merge_loop<false>(vol, trip, prev, tM[0], tM[1], tM[2],
                                    dl[0], dl[1], dl[2], src[0], src[1], src[2],
                                    spn[0], spn[1], spn[2], sdd[0], sdd[1], sdd[2]);
        }
    }
    atomicAdd(&out[it * WW + is], acc * sqrtf(nrm2));
}

extern "C" void kernel_launch(void* const* d_in, const int* in_sizes, int n_in,
                              void* d_out, int out_size, void* d_ws, size_t ws_size,
                              hipStream_t stream)
{
    const float* vol     = (const float*)d_in[0];
    const float* spacing = (const float*)d_in[1];
    const float* sdr     = (const float*)d_in[2];
    const float* theta   = (const float*)d_in[3];
    const float* phi     = (const float*)d_in[4];
    const float* gamma   = (const float*)d_in[5];
    const float* bx      = (const float*)d_in[6];
    const float* by      = (const float*)d_in[7];
    const float* bz      = (const float*)d_in[8];
    float* out = (float*)d_out;

    if (ws_size >= WS_BYTES) {
        float* ws = (float*)d_ws;
        drr_pre<<<RBLK, 256, 0, stream>>>(spacing, sdr, theta, phi, gamma,
                                          bx, by, bz, ws);
        drr_main<<<NWG, 256, 0, stream>>>(vol, ws);
        drr_fin<<<RBLK, 256, 0, stream>>>(ws, out);
    } else {
        hipMemsetAsync(out, 0, (size_t)out_size * sizeof(float), stream);
        drr_mono<<<NWG, 256, 0, stream>>>(vol, spacing, sdr, theta, phi, gamma,
                                          bx, by, bz, out);
    }
}